// Round 4
// baseline (5347.504 us; speedup 1.0000x reference)
//
#include <hip/hip_runtime.h>

#define Bn 256
#define Tn 2048
#define Dn 40
#define Hn 128
#define Cn 35

typedef _Float16 h2 __attribute__((ext_vector_type(2)));
typedef int int4v __attribute__((ext_vector_type(4)));

__device__ __forceinline__ int imin(int a, int b) { return a < b ? a : b; }

__device__ __forceinline__ int sdot4(int a, int b, int c) {
#if __has_builtin(__builtin_amdgcn_sdot4)
  return __builtin_amdgcn_sdot4(a, b, c, false);
#else
  int r = c;
#pragma unroll
  for (int i = 0; i < 4; ++i)
    r += ((int)(a << (24 - 8 * i)) >> 24) * ((int)(b << (24 - 8 * i)) >> 24);
  return r;
#endif
}

__device__ __forceinline__ float fdot2f(h2 a, h2 b, float c) {
#if __has_builtin(__builtin_amdgcn_fdot2)
  return __builtin_amdgcn_fdot2(a, b, c, false);
#else
  return c + (float)(a[0]) * (float)(b[0]) + (float)(a[1]) * (float)(b[1]);
#endif
}

__device__ __forceinline__ h2 bch(int u) { return __builtin_bit_cast(h2, u); }

__device__ __forceinline__ int pk2i(float a, float b) {  // two f16 in one word
  h2 r; r[0] = (_Float16)a; r[1] = (_Float16)b;
  return __builtin_bit_cast(int, r);
}

__device__ __forceinline__ float rcpf_(float x) {
#if __has_builtin(__builtin_amdgcn_rcpf)
  return __builtin_amdgcn_rcpf(x);
#else
  return 1.f / x;
#endif
}

__device__ __forceinline__ float sigm(float v) {
  v = fmaxf(fminf(v, 60.f), -60.f);
  return rcpf_(1.f + __expf(-v));
}

__device__ __forceinline__ float tanha(float v) {
  v = fmaxf(fminf(v, 15.f), -15.f);
  const float e = __expf(2.f * v);
  return (e - 1.f) * rcpf_(e + 1.f);
}

__device__ __forceinline__ int q8c(float v) {  // round+clamp to [-127,127]
  v = fminf(fmaxf(v, -127.f), 127.f);
  return (int)__builtin_rintf(v);
}

__device__ __forceinline__ int pk4(int a, int b, int c, int d) {
  return (a & 255) | ((b & 255) << 8) | ((c & 255) << 16) | (d << 24);
}

// DPP quad-perm xor-1 / xor-2 (full-rate VALU cross-lane within quads)
__device__ __forceinline__ int dpp_x1(int v) {
  return __builtin_amdgcn_update_dpp(0, v, 0xB1, 0xF, 0xF, true);
}
__device__ __forceinline__ int dpp_x2(int v) {
  return __builtin_amdgcn_update_dpp(0, v, 0x4E, 0xF, 0xF, true);
}

#if __has_builtin(__builtin_amdgcn_global_load_lds)
#define HAVE_GLDS 1
__device__ __forceinline__ void gl_lds16(const float* g, float* l) {
  __builtin_amdgcn_global_load_lds(
      (const __attribute__((address_space(1))) unsigned int*)(const void*)g,
      (__attribute__((address_space(3))) unsigned int*)(void*)l, 16, 0, 0);
}
#endif

// quantize 128 f32 weights -> 32 packed-i8 words + scale (rowmax/127)
__device__ __forceinline__ void quantW128(const float* __restrict__ p,
                                          int* __restrict__ q, float& sc) {
  float m = 1e-30f;
#pragma unroll
  for (int i = 0; i < 32; ++i) {
    const float4 v = reinterpret_cast<const float4*>(p)[i];
    m = fmaxf(m, fmaxf(fmaxf(fabsf(v.x), fabsf(v.y)),
                       fmaxf(fabsf(v.z), fabsf(v.w))));
  }
  const float inv = 127.f / m;
  sc = m * (1.f / 127.f);
#pragma unroll
  for (int i = 0; i < 32; ++i) {
    const float4 v = reinterpret_cast<const float4*>(p)[i];
    q[i] = pk4(q8c(v.x * inv), q8c(v.y * inv), q8c(v.z * inv), q8c(v.w * inv));
  }
}

// readlane word w (0..319) from 5-reg stash (lane L holds flat[L+64k])
#define RLST(w) __builtin_amdgcn_readlane(                                  \
    ((w) < 64 ? st0 : (w) < 128 ? st1 : (w) < 192 ? st2 : (w) < 256 ? st3  \
                                                        : st4), (w) & 63)

#define MEMBAR() asm volatile("" ::: "memory")

// r10: register-budget-honest r9. r9's VGPR_Count=188 vs the ~280 its L0
// wave NEEDS (q0..q7[32] = 256 ints) => the allocator demoted weights to
// AGPR/scratch, inserting a move/load before every sdot4 -- the ~2200cy/step
// unexplained stall (r6's 86MB WRITE_SIZE = the same bug as scratch stores).
// Fix: 8 waves (2/SIMD, 256-VGPR cap), every heavy role split in half so
// each wave holds 4 rows/lane = 128 weight VGPRs (~170 total, fits):
//   w0/w1 L0a/L0b (units 0-63 / 64-127; ONE cell/lane -> act balanced)
//   w2/w3 L1a/L1b          w4/w5 TERMa/b (Wih1)      w6/w7 XPa/b (Wih0)
// Each L-half keeps its own 16 h-words in-register (DPP pack); partner's 16
// words via one broadcast LDS read. The a<->b edge is distance-1 symmetric
// (a(t+1)<-b(t)<-a(t-1)): costs publish->poll visibility only, no
// serialization (the r8 bug was helper(t) needing L0(t) COMPLETE).
// Readlanes hoisted in blocks of 16 ahead of their 64 sdot4s.
// XP pair: 2-phase flag (2k+1 = chunk k projected, 2k+2 = chunk k+1
// converted) closes the shared-s_xh2 race between the two XP halves.
// Flag protocol otherwise identical to r9 (proven): publish = lgkmcnt(0) +
// ds_write; monotone counters; cached polls.
__global__ __launch_bounds__(512, 2) void lstm2_fused(
    const float* __restrict__ x,
    const int*   __restrict__ length,
    const float* __restrict__ Wih0, const float* __restrict__ Whh0,
    const float* __restrict__ bih0, const float* __restrict__ bhh0,
    const float* __restrict__ Wih1, const float* __restrict__ Whh1,
    const float* __restrict__ bih1, const float* __restrict__ bhh1,
    const float* __restrict__ gam,  const float* __restrict__ bet,
    const float* __restrict__ fcw,  const float* __restrict__ fcb,
    float* __restrict__ out)
{
  __shared__ __align__(16) float s_xraw[160 * 4];  // 2.5 KiB raw x chunk
  __shared__ int   s_xh2[320];                     // 1.25 KiB f16 x chunk
  __shared__ float s_xp[2][16][8][64];             // 64 KiB x-projection
  __shared__ float s_term[4][4][2][64];            // 8 KiB ih-term ring
  __shared__ int   s_h0q[4][32];                   // 4-deep packed i8 h0 ring
  __shared__ int   s_h1q[4][32];                   // 4-deep packed i8 h1 ring
  __shared__ __align__(32) int s_flag[8];          // L0a,L0b,L1a,L1b,Ta,Tb,Xa,Xb
  __shared__ float s_h1f[128];
  __shared__ float s_hn[128];

  const int tid  = threadIdx.x;
  const int lane = tid & 63;
  const int wv   = tid >> 6;          // wave 0..7
  const int b    = blockIdx.x;
  const int len  = length[b];         // 1..2048

  // ---- chunk-0 raw prefetch (XP waves; hidden under zero-init) ----
  if (wv == 6) {
    const float* xs = x + (size_t)b * Tn * Dn;
#if HAVE_GLDS
    gl_lds16(xs + lane * 4,        &s_xraw[0]);
    gl_lds16(xs + (lane + 64) * 4, &s_xraw[256]);
#else
    *(float4*)&s_xraw[lane * 4] = *(const float4*)(xs + lane * 4);
    *(float4*)&s_xraw[(lane + 64) * 4] = *(const float4*)(xs + (lane + 64) * 4);
#endif
  } else if (wv == 7 && lane < 32) {
    const float* xs = x + (size_t)b * Tn * Dn;
#if HAVE_GLDS
    gl_lds16(xs + (lane + 128) * 4, &s_xraw[512]);
#else
    *(float4*)&s_xraw[(lane + 128) * 4] = *(const float4*)(xs + (lane + 128) * 4);
#endif
  }
  if (tid < 128) { ((int*)s_h0q)[tid] = 0; ((int*)s_h1q)[tid] = 0; }
  if (tid < 8) s_flag[tid] = 0;
  __syncthreads();                 // glds drained; zeros visible
  if (tid < 160) {                 // convert chunk 0 to f16 stash
    const float4 v = *(const float4*)&s_xraw[4 * tid];
    s_xh2[2 * tid]     = pk2i(v.x, v.y);
    s_xh2[2 * tid + 1] = pk2i(v.z, v.w);
  }
  __syncthreads();                 // stash ready for both XP halves

  const __attribute__((address_space(3))) int* flagp3 =
      (const __attribute__((address_space(3))) int*)(const void*)s_flag;
  int4v f03 = {0, 0, 0, 0}, f47 = {0, 0, 0, 0};

#define READFLAGS()                                                          \
  asm volatile("ds_read_b128 %0, %2\n\tds_read_b128 %1, %2 offset:16\n\t"    \
               "s_waitcnt lgkmcnt(0)"                                        \
               : "=v"(f03), "=v"(f47) : "v"(flagp3) : "memory")
#define PUBLISH(idx, val)                                                    \
  do {                                                                       \
    MEMBAR();                                                                \
    asm volatile("s_waitcnt lgkmcnt(0)" ::: "memory");                       \
    *(volatile int*)&s_flag[idx] = (val);                                    \
  } while (0)
#define POLL(COND)                                                           \
  do {                                                                       \
    if (!(COND)) {                                                           \
      for (;;) {                                                             \
        READFLAGS();                                                         \
        if (COND) break;                                                     \
        __builtin_amdgcn_s_sleep(1);                                         \
      }                                                                      \
    }                                                                        \
    MEMBAR();                                                                \
  } while (0)

  if (wv < 2) {
    // ================= L0 half (units 64*half .. 64*half+63) =============
    const int half = wv;
    const int u = (half << 6) | lane;
    int qI[32], qF[32], qG[32], qO[32];
    float sI, sF, sG, sO;
    quantW128(Whh0 + (size_t)u * Hn, qI, sI);
    quantW128(Whh0 + (size_t)(u + 128) * Hn, qF, sF);
    quantW128(Whh0 + (size_t)(u + 256) * Hn, qG, sG);
    quantW128(Whh0 + (size_t)(u + 384) * Hn, qO, sO);
    sI *= (1.f / 127.f); sF *= (1.f / 127.f);
    sG *= (1.f / 127.f); sO *= (1.f / 127.f);
    const float bI = bih0[u]       + bhh0[u];
    const float bF = bih0[u + 128] + bhh0[u + 128];
    const float bG = bih0[u + 256] + bhh0[u + 256];
    const float bO = bih0[u + 384] + bhh0[u + 384];
    const int jo = half << 4, jp = (half ^ 1) << 4;
    float c0 = 0.f;
    int wA = 0;  // own 16 packed words (word jo+q at quad q lanes)
#pragma unroll 1
    for (int t = 0; t < len; ++t) {
      const int tl = t & 15;
      POLL(f03[half ^ 1] >= t && imin(f47[0], f47[1]) >= t - 3 &&
           (tl != 0 || imin(f47[2], f47[3]) >= 2 * (t >> 4) + 1));
      // partner h0 half (words jp..jp+15), broadcast read
      const int pw = s_h0q[(t + 3) & 3][jp + (lane & 15)];
      const int cs = (t >> 4) & 1;
      const float xI = s_xp[cs][tl][half][lane];
      const float xF = s_xp[cs][tl][half + 2][lane];
      const float xG = s_xp[cs][tl][half + 4][lane];
      const float xO = s_xp[cs][tl][half + 6][lane];
      int aI = 0, aF = 0, aG = 0, aO = 0;
      {
        int sw[16];
#pragma unroll
        for (int j = 0; j < 16; ++j) sw[j] = __builtin_amdgcn_readlane(wA, 4 * j);
#pragma unroll
        for (int j = 0; j < 16; ++j) {
          aI = sdot4(sw[j], qI[jo + j], aI); aF = sdot4(sw[j], qF[jo + j], aF);
          aG = sdot4(sw[j], qG[jo + j], aG); aO = sdot4(sw[j], qO[jo + j], aO);
        }
#pragma unroll
        for (int j = 0; j < 16; ++j) sw[j] = __builtin_amdgcn_readlane(pw, j);
#pragma unroll
        for (int j = 0; j < 16; ++j) {
          aI = sdot4(sw[j], qI[jp + j], aI); aF = sdot4(sw[j], qF[jp + j], aF);
          aG = sdot4(sw[j], qG[jp + j], aG); aO = sdot4(sw[j], qO[jp + j], aO);
        }
      }
      const float gi = bI + xI + (float)aI * sI;
      const float gf = bF + xF + (float)aF * sF;
      const float gg = bG + xG + (float)aG * sG;
      const float go = bO + xO + (float)aO * sO;
      c0 = sigm(gf) * c0 + sigm(gi) * tanha(gg);
      const float h = sigm(go) * tanha(c0);
      int v = (((int)__builtin_rintf(h * 127.f)) & 255) << (8 * (lane & 3));
      v |= dpp_x1(v); v |= dpp_x2(v);
      wA = v;
      if ((lane & 3) == 0) s_h0q[t & 3][jo + (lane >> 2)] = v;
      PUBLISH(wv, t + 1);
      READFLAGS();
    }
  } else if (wv < 4) {
    // ================= L1 half =================
    const int half = wv - 2;
    const int u = (half << 6) | lane;
    int qI[32], qF[32], qG[32], qO[32];
    float sI, sF, sG, sO;
    quantW128(Whh1 + (size_t)u * Hn, qI, sI);
    quantW128(Whh1 + (size_t)(u + 128) * Hn, qF, sF);
    quantW128(Whh1 + (size_t)(u + 256) * Hn, qG, sG);
    quantW128(Whh1 + (size_t)(u + 384) * Hn, qO, sO);
    sI *= (1.f / 127.f); sF *= (1.f / 127.f);
    sG *= (1.f / 127.f); sO *= (1.f / 127.f);
    const int jo = half << 4, jp = (half ^ 1) << 4;
    float c1 = 0.f;
    int wA = 0;
#pragma unroll 1
    for (int t = 0; t < len; ++t) {
      POLL(f03[2 + (half ^ 1)] >= t && imin(f47[0], f47[1]) >= t + 1);
      const int pw = s_h1q[(t + 3) & 3][jp + (lane & 15)];
      const float tvI = s_term[t & 3][0][half][lane];
      const float tvF = s_term[t & 3][1][half][lane];
      const float tvG = s_term[t & 3][2][half][lane];
      const float tvO = s_term[t & 3][3][half][lane];
      int aI = 0, aF = 0, aG = 0, aO = 0;
      {
        int sw[16];
#pragma unroll
        for (int j = 0; j < 16; ++j) sw[j] = __builtin_amdgcn_readlane(wA, 4 * j);
#pragma unroll
        for (int j = 0; j < 16; ++j) {
          aI = sdot4(sw[j], qI[jo + j], aI); aF = sdot4(sw[j], qF[jo + j], aF);
          aG = sdot4(sw[j], qG[jo + j], aG); aO = sdot4(sw[j], qO[jo + j], aO);
        }
#pragma unroll
        for (int j = 0; j < 16; ++j) sw[j] = __builtin_amdgcn_readlane(pw, j);
#pragma unroll
        for (int j = 0; j < 16; ++j) {
          aI = sdot4(sw[j], qI[jp + j], aI); aF = sdot4(sw[j], qF[jp + j], aF);
          aG = sdot4(sw[j], qG[jp + j], aG); aO = sdot4(sw[j], qO[jp + j], aO);
        }
      }
      const float gi = tvI + (float)aI * sI;
      const float gf = tvF + (float)aF * sF;
      const float gg = tvG + (float)aG * sG;
      const float go = tvO + (float)aO * sO;
      c1 = sigm(gf) * c1 + sigm(gi) * tanha(gg);
      const float h = sigm(go) * tanha(c1);
      if (t == len - 1) s_h1f[u] = h;
      int v = (((int)__builtin_rintf(h * 127.f)) & 255) << (8 * (lane & 3));
      v |= dpp_x1(v); v |= dpp_x2(v);
      wA = v;
      if ((lane & 3) == 0) s_h1q[t & 3][jo + (lane >> 2)] = v;
      PUBLISH(wv, t + 1);
      READFLAGS();
    }
  } else if (wv < 6) {
    // ================= TERM half: Wih1 . h0(t) for units of this half ====
    const int half = wv - 4;
    const int u = (half << 6) | lane;
    int qI[32], qF[32], qG[32], qO[32];
    float sI, sF, sG, sO;
    quantW128(Wih1 + (size_t)u * Hn, qI, sI);
    quantW128(Wih1 + (size_t)(u + 128) * Hn, qF, sF);
    quantW128(Wih1 + (size_t)(u + 256) * Hn, qG, sG);
    quantW128(Wih1 + (size_t)(u + 384) * Hn, qO, sO);
    sI *= (1.f / 127.f); sF *= (1.f / 127.f);
    sG *= (1.f / 127.f); sO *= (1.f / 127.f);
    const float bI = bih1[u]       + bhh1[u];
    const float bF = bih1[u + 128] + bhh1[u + 128];
    const float bG = bih1[u + 256] + bhh1[u + 256];
    const float bO = bih1[u + 384] + bhh1[u + 384];
#pragma unroll 1
    for (int t = 0; t < len; ++t) {
      POLL(f03[0] >= t + 1 && f03[1] >= t + 1 &&
           imin(f03[2], f03[3]) >= t - 3);
      const int vq = s_h0q[t & 3][lane & 31];  // full 32-word h0(t)
      int aI = 0, aF = 0, aG = 0, aO = 0;
      {
        int sw[32];
#pragma unroll
        for (int j = 0; j < 32; ++j) sw[j] = __builtin_amdgcn_readlane(vq, j);
#pragma unroll
        for (int j = 0; j < 32; ++j) {
          aI = sdot4(sw[j], qI[j], aI); aF = sdot4(sw[j], qF[j], aF);
          aG = sdot4(sw[j], qG[j], aG); aO = sdot4(sw[j], qO[j], aO);
        }
      }
      s_term[t & 3][0][half][lane] = bI + (float)aI * sI;
      s_term[t & 3][1][half][lane] = bF + (float)aF * sF;
      s_term[t & 3][2][half][lane] = bG + (float)aG * sG;
      s_term[t & 3][3][half][lane] = bO + (float)aO * sO;
      PUBLISH(wv, t + 1);
      READFLAGS();
    }
  } else {
    // ================= XP half: x -> f16 -> Wih0 rows of this half =======
    const int half = wv - 6;
    const int u = (half << 6) | lane;  // same rows as L0 half
    int wpA[20], wpB[20], wpC[20], wpD[20];
    {
      const float* p;
      p = Wih0 + (size_t)u * Dn;
#pragma unroll
      for (int w2 = 0; w2 < 20; ++w2) wpA[w2] = pk2i(p[2 * w2], p[2 * w2 + 1]);
      p = Wih0 + (size_t)(u + 128) * Dn;
#pragma unroll
      for (int w2 = 0; w2 < 20; ++w2) wpB[w2] = pk2i(p[2 * w2], p[2 * w2 + 1]);
      p = Wih0 + (size_t)(u + 256) * Dn;
#pragma unroll
      for (int w2 = 0; w2 < 20; ++w2) wpC[w2] = pk2i(p[2 * w2], p[2 * w2 + 1]);
      p = Wih0 + (size_t)(u + 384) * Dn;
#pragma unroll
      for (int w2 = 0; w2 < 20; ++w2) wpD[w2] = pk2i(p[2 * w2], p[2 * w2 + 1]);
    }
    const int nch = (len + 15) >> 4;
#pragma unroll 1
    for (int k = 0; k < nch; ++k) {
      const bool more = (k + 1 < nch);
      if (more) {  // prefetch raw chunk k+1 (own segments)
        const float* xs = x + ((size_t)b * Tn + (size_t)(k + 1) * 16) * Dn;
        if (half == 0) {
#if HAVE_GLDS
          gl_lds16(xs + lane * 4,        &s_xraw[0]);
          gl_lds16(xs + (lane + 64) * 4, &s_xraw[256]);
#else
          *(float4*)&s_xraw[lane * 4] = *(const float4*)(xs + lane * 4);
          *(float4*)&s_xraw[(lane + 64) * 4] = *(const float4*)(xs + (lane + 64) * 4);
#endif
        } else if (lane < 32) {
#if HAVE_GLDS
          gl_lds16(xs + (lane + 128) * 4, &s_xraw[512]);
#else
          *(float4*)&s_xraw[(lane + 128) * 4] = *(const float4*)(xs + (lane + 128) * 4);
#endif
        }
      }
      // project chunk k (partner must have converted chunk k: flag >= 2k)
      POLL(f47[2 + (half ^ 1)] >= 2 * k);
      {
        const int* flat = s_xh2;
        const int st0 = flat[lane], st1 = flat[lane + 64],
                  st2 = flat[lane + 128], st3 = flat[lane + 192],
                  st4 = flat[lane + 256];
#pragma unroll 1
        for (int tl = 0; tl < 16; ++tl) {
          float a0 = 0.f, a1 = 0.f, a2 = 0.f, a3 = 0.f;
#pragma unroll
          for (int w2 = 0; w2 < 20; ++w2) {
            const h2 s = bch(RLST(20 * tl + w2));
            a0 = fdot2f(s, bch(wpA[w2]), a0);
            a1 = fdot2f(s, bch(wpB[w2]), a1);
            a2 = fdot2f(s, bch(wpC[w2]), a2);
            a3 = fdot2f(s, bch(wpD[w2]), a3);
          }
          s_xp[k & 1][tl][half][lane]     = a0;
          s_xp[k & 1][tl][half + 2][lane] = a1;
          s_xp[k & 1][tl][half + 4][lane] = a2;
          s_xp[k & 1][tl][half + 6][lane] = a3;
        }
      }
      PUBLISH(wv, 2 * k + 1);
      if (more) {
        // convert chunk k+1 into shared stash: needs L0 past the buffer we
        // overwrite next AND partner done projecting chunk k from s_xh2
        POLL(imin(f03[0], f03[1]) >= 16 * k &&
             f47[2 + (half ^ 1)] >= 2 * k + 1);
#if HAVE_GLDS
        asm volatile("s_waitcnt vmcnt(0)" ::: "memory");
#endif
        if (half == 0) {
          float4 v = *(const float4*)&s_xraw[4 * lane];
          s_xh2[2 * lane] = pk2i(v.x, v.y);
          s_xh2[2 * lane + 1] = pk2i(v.z, v.w);
          v = *(const float4*)&s_xraw[4 * (lane + 64)];
          s_xh2[2 * (lane + 64)] = pk2i(v.x, v.y);
          s_xh2[2 * (lane + 64) + 1] = pk2i(v.z, v.w);
        } else if (lane < 32) {
          float4 v = *(const float4*)&s_xraw[4 * (lane + 128)];
          s_xh2[2 * (lane + 128)] = pk2i(v.x, v.y);
          s_xh2[2 * (lane + 128) + 1] = pk2i(v.z, v.w);
        }
      }
      PUBLISH(wv, 2 * k + 2);
      READFLAGS();
    }
  }

  __syncthreads();  // all chains done; s_h1f complete

  // ---- LayerNorm over H on wave 0 ----
  if (tid < 64) {
    const float a = s_h1f[tid], d = s_h1f[64 + tid];
    float s = a + d, q = a * a + d * d;
#pragma unroll
    for (int m = 32; m >= 1; m >>= 1) {
      s += __shfl_xor(s, m, 64);
      q += __shfl_xor(q, m, 64);
    }
    const float mu = s * (1.f / 128.f);
    float var = q * (1.f / 128.f) - mu * mu;
    var = fmaxf(var, 0.f);
    const float rstd = rsqrtf(var + 1e-5f);
    s_hn[tid]      = (a - mu) * rstd * gam[tid]      + bet[tid];
    s_hn[64 + tid] = (d - mu) * rstd * gam[64 + tid] + bet[64 + tid];
  }
  __syncthreads();

  // ---- FC head ----
  if (tid < Cn) {
    float acc = fcb[tid];
    const float* wp = fcw + tid * Hn;
#pragma unroll 4
    for (int k = 0; k < Hn; ++k) acc += s_hn[k] * wp[k];
    out[(size_t)b * Cn + tid] = acc;
  }
}

extern "C" void kernel_launch(void* const* d_in, const int* in_sizes, int n_in,
                              void* d_out, int out_size, void* d_ws, size_t ws_size,
                              hipStream_t stream) {
  (void)in_sizes; (void)n_in; (void)d_ws; (void)ws_size; (void)out_size;
  lstm2_fused<<<dim3(Bn), dim3(512), 0, stream>>>(
      (const float*)d_in[0],  (const int*)d_in[1],
      (const float*)d_in[2],  (const float*)d_in[3],
      (const float*)d_in[4],  (const float*)d_in[5],
      (const float*)d_in[6],  (const float*)d_in[7],
      (const float*)d_in[8],  (const float*)d_in[9],
      (const float*)d_in[10], (const float*)d_in[11],
      (const float*)d_in[12], (const float*)d_in[13],
      (float*)d_out);
}